// Round 21
// baseline (51.287 us; speedup 1.0000x reference)
//
#include <hip/hip_runtime.h>
#include <hip/hip_bf16.h>

#define T_DIM 2048
#define B_DIM 2
#define E_DIM 256
#define H_DIM 8
#define D_DIM 32
#define M_DIM (T_DIM*B_DIM)   // 4096

typedef __bf16 bf16x8 __attribute__((ext_vector_type(8)));
typedef __bf16 bf16x4 __attribute__((ext_vector_type(4)));
typedef __bf16 bf16x2 __attribute__((ext_vector_type(2)));
typedef float  f32x4  __attribute__((ext_vector_type(4)));

// single-instruction hardware exp2 via compiler builtin (hazards handled by codegen)
static __device__ __forceinline__ float fexp2(float x) {
#if __has_builtin(__builtin_amdgcn_exp2f)
    return __builtin_amdgcn_exp2f(x);
#else
    return exp2f(x);
#endif
}

// ---------------- Kernel 1: fused QKV projection (inline f32->bf16 cvt) ----------------
// grid (64, 12). K and V are written PRE-PERMUTED into MFMA-fragment-linear order:
//   kperm[bh][til][nt][lane]{8}  : lane(lr,lg) holds K[s = til*64+(nt>>1)*32+(nt&1)*4+perm(lr)][lg*8..+7]
//   vperm[bh][til][j ][lane]{8}  : j=kt*2+dt, lane(lr,lg) holds V^T[d=dt*16+lr][s = til*64+kt*32+lg*8..+7]
// q is pre-scaled by (1/sqrt(D))*log2(e) so the QK^T MFMA directly yields log2-domain scores.
// Epilogue routes the permuted scatter through LDS: per-element LDS writes at the permuted
// offsets, then coalesced bf16x8 global stores of the four contiguous 2KB chunks per block.
__global__ __launch_bounds__(256)
void qkv_kernel(const float* __restrict__ X,
                const float* __restrict__ Wq, const float* __restrict__ Wk, const float* __restrict__ Wv,
                const float* __restrict__ bq, const float* __restrict__ bk, const float* __restrict__ bv,
                __bf16* __restrict__ qh, __bf16* __restrict__ kperm, __bf16* __restrict__ vperm) {
    __shared__ __align__(16) __bf16 Xs[64][136];
    __shared__ __align__(16) __bf16 Ws[64][136];
    __shared__ __align__(16) __bf16 Ps[4][1024];   // staged permuted output (4 x 2KB chunks)
    const int m0 = blockIdx.x * 64;
    const int which = blockIdx.y >> 2;        // 0 q, 1 k, 2 v
    const int n0 = (blockIdx.y & 3) * 64;
    const float* W = (which == 0) ? Wq : (which == 1) ? Wk : Wv;
    const float* bias = (which == 0) ? bq : (which == 1) ? bk : bv;
    const int tid = threadIdx.x;
    const int wid = tid >> 6, lane = tid & 63;
    const int wm = (wid & 1) * 32, wn = (wid >> 1) * 32;
    const int lr = lane & 15, lg = lane >> 4;

    f32x4 acc[2][2] = {};
    for (int kc = 0; kc < 2; ++kc) {
        for (int c = tid; c < 2048; c += 256) {
            int row = c >> 5, col = (c & 31) * 4;
            float4 xv = *(const float4*)&X[(size_t)(m0 + row) * E_DIM + kc * 128 + col];
            float4 wv = *(const float4*)&W[(size_t)(n0 + row) * E_DIM + kc * 128 + col];
            bf16x4 xb, wb;
            xb[0] = (__bf16)xv.x; xb[1] = (__bf16)xv.y; xb[2] = (__bf16)xv.z; xb[3] = (__bf16)xv.w;
            wb[0] = (__bf16)wv.x; wb[1] = (__bf16)wv.y; wb[2] = (__bf16)wv.z; wb[3] = (__bf16)wv.w;
            *(bf16x4*)&Xs[row][col] = xb;
            *(bf16x4*)&Ws[row][col] = wb;
        }
        __syncthreads();
#pragma unroll
        for (int ks = 0; ks < 4; ++ks) {
            bf16x8 a0 = *(const bf16x8*)&Xs[wm + lr][ks * 32 + lg * 8];
            bf16x8 a1 = *(const bf16x8*)&Xs[wm + 16 + lr][ks * 32 + lg * 8];
            bf16x8 b0 = *(const bf16x8*)&Ws[wn + lr][ks * 32 + lg * 8];
            bf16x8 b1 = *(const bf16x8*)&Ws[wn + 16 + lr][ks * 32 + lg * 8];
            acc[0][0] = __builtin_amdgcn_mfma_f32_16x16x32_bf16(a0, b0, acc[0][0], 0, 0, 0);
            acc[0][1] = __builtin_amdgcn_mfma_f32_16x16x32_bf16(a0, b1, acc[0][1], 0, 0, 0);
            acc[1][0] = __builtin_amdgcn_mfma_f32_16x16x32_bf16(a1, b0, acc[1][0], 0, 0, 0);
            acc[1][1] = __builtin_amdgcn_mfma_f32_16x16x32_bf16(a1, b1, acc[1][1], 0, 0, 0);
        }
        __syncthreads();
    }
    const float scale = 0.17677669529663687f * 1.4426950408889634f;  // (1/sqrt(32))*log2(e)
    const int tb = m0 >> 1;                   // first t of this block (multiple of 32)
    const int hl0 = n0 >> 5;                  // first head index covered (even)

    // epilogue phase 1: element-wise permuted scatter INTO LDS
#pragma unroll
    for (int mt = 0; mt < 2; ++mt) {
#pragma unroll
        for (int nt = 0; nt < 2; ++nt) {
            int n = n0 + wn + nt * 16 + lr;            // 0..255
            float bb = bias[n];
            int hl = (n >> 5) - hl0, d = n & 31;       // hl in {0,1}
#pragma unroll
            for (int r = 0; r < 4; ++r) {
                int m = m0 + wm + mt * 16 + lg * 4 + r;
                int tt = (m >> 1) - tb, b = m & 1;     // tt in 0..31
                float v = acc[mt][nt][r] + bb;
                int off;
                if (which == 0) {
                    v *= scale;
                    off = tt * 32 + d;
                } else if (which == 1) {
                    off = ((tt >> 2) & 1) * 512 +
                          ((((d >> 3) << 4) | (((tt >> 3) & 3) << 2) | (tt & 3)) << 3) + (d & 7);
                } else {
                    off = (d >> 4) * 512 +
                          (((((tt >> 3) & 3) << 4) | (d & 15)) << 3) + (tt & 7);
                }
                Ps[b * 2 + hl][off] = (__bf16)v;
            }
        }
    }
    __syncthreads();

    // epilogue phase 2: coalesced copy-out (each chunk is contiguous 2KB in the dst array)
    {
        int combo = tid >> 6, e0 = (tid & 63) * 16;    // 64 threads per 1024-elem chunk
        int bc = combo >> 1, hl = combo & 1;
        int bh = bc * H_DIM + hl0 + hl;
        int til = tb >> 6;
        __bf16* dst;
        if (which == 0) {
            dst = qh + ((size_t)bh * T_DIM + tb) * D_DIM;
        } else if (which == 1) {
            int ntk0 = ((tb >> 5) & 1) << 1;
            dst = kperm + (((size_t)bh * 32 + til) * 4 + ntk0) * 512;
        } else {
            int ktv = (tb >> 5) & 1;
            dst = vperm + (((size_t)bh * 32 + til) * 4 + ktv * 2) * 512;
        }
        *(bf16x8*)(dst + e0)     = *(const bf16x8*)&Ps[combo][e0];
        *(bf16x8*)(dst + e0 + 8) = *(const bf16x8*)&Ps[combo][e0 + 8];
    }
}

// ---------------- Kernel 2: flash attention, SINGLE-PASS (no split, no partials) ----------------
// grid 256 blocks (T/16 x B, 1/CU), block 512 = 8 waves; wave w = head w, 16 q-rows, full S.
// b = lin&1 pins each XCD (lin%8) to one batch -> K/V working set 2MB/XCD, L2-resident.
// Bias tile [16][2048] f32 = 128.3KB LDS, staged once as (bias-12)*log2(e) (read-once HBM);
// q pre-scaled by log2(e)/sqrt(D) so QK^T MFMA output IS log2(p); exp2 = single v_exp_f32.
// Fixed cap M0=12 exact (common scale cancels). Row-sums via ones-MFMA; normalization
// happens in-kernel -> writes the 2MB att buffer directly (po/pl round-trip eliminated).
// Per-wave rotated tile order (order-independent sums).
__global__ __launch_bounds__(512, 4)
void attn_kernel(const __bf16* __restrict__ qh, const __bf16* __restrict__ kperm,
                 const __bf16* __restrict__ vperm, const float* __restrict__ attn_bias,
                 __bf16* __restrict__ att) {
    __shared__ __align__(16) float Bs[16][2052];
    const int lin = blockIdx.x;
    const int b  = lin & 1;
    const int t0 = (lin >> 1) * 16;
    const int tid = threadIdx.x, wid = tid >> 6, lane = tid & 63;
    const int lr = lane & 15, lg = lane >> 4;
    const int bh = b * H_DIM + wid;            // wave = head
    const float LOG2E = 1.4426950408889634f;

    // stage bias tile [16][2048] as (b - 12)*log2(e) (all 8 heads share it)
    {
        const float* bsrc = attn_bias + ((size_t)b * T_DIM + t0) * T_DIM;
#pragma unroll
        for (int rep = 0; rep < 16; ++rep) {
            int c = tid + rep * 512;           // 0..8191 float4 chunks
            int row = c >> 9, col = (c & 511) * 4;
            float4 v = *(const float4*)&bsrc[(size_t)row * T_DIM + col];
            float4 w;
            w.x = (v.x - 12.0f) * LOG2E;
            w.y = (v.y - 12.0f) * LOG2E;
            w.z = (v.z - 12.0f) * LOG2E;
            w.w = (v.w - 12.0f) * LOG2E;
            *(float4*)&Bs[row][col] = w;
        }
    }
    __syncthreads();

    bf16x8 qf = *(const bf16x8*)&qh[((size_t)bh * T_DIM + t0 + lr) * D_DIM + lg * 8];
    const __bf16* kpb = kperm + (size_t)bh * T_DIM * D_DIM + (size_t)lane * 8;
    const __bf16* vpb = vperm + (size_t)bh * T_DIM * D_DIM + (size_t)lane * 8;

    bf16x8 ones;
#pragma unroll
    for (int i = 0; i < 8; ++i) ones[i] = (__bf16)1.0f;

    f32x4 o0 = {}, o1 = {};   // o[dt][r]: row t = t0+lg*4+r, col d = dt*16+lr
    f32x4 ol = {};            // row-sum accumulator

#pragma unroll 4
    for (int st = 0; st < 32; ++st) {
        const int til = (st + wid * 4) & 31;   // per-wave rotated tile order

        // K + V fragment loads: linear, 16B/lane, L2-resident (XCD-pinned batch)
        bf16x8 kf0 = *(const bf16x8*)&kpb[(size_t)(til * 4 + 0) * 512];
        bf16x8 kf1 = *(const bf16x8*)&kpb[(size_t)(til * 4 + 1) * 512];
        bf16x8 kf2 = *(const bf16x8*)&kpb[(size_t)(til * 4 + 2) * 512];
        bf16x8 kf3 = *(const bf16x8*)&kpb[(size_t)(til * 4 + 3) * 512];
        bf16x8 vf0 = *(const bf16x8*)&vpb[(size_t)(til * 4 + 0) * 512];
        bf16x8 vf1 = *(const bf16x8*)&vpb[(size_t)(til * 4 + 1) * 512];
        bf16x8 vf2 = *(const bf16x8*)&vpb[(size_t)(til * 4 + 2) * 512];
        bf16x8 vf3 = *(const bf16x8*)&vpb[(size_t)(til * 4 + 3) * 512];

        // bias C-operands from LDS: row = lr, col = til*64 + (nt>>1)*32 + lg*8 + (nt&1)*4
        f32x4 cb0 = *(const f32x4*)&Bs[lr][til * 64 +  0 + lg * 8 + 0];
        f32x4 cb1 = *(const f32x4*)&Bs[lr][til * 64 +  0 + lg * 8 + 4];
        f32x4 cb2 = *(const f32x4*)&Bs[lr][til * 64 + 32 + lg * 8 + 0];
        f32x4 cb3 = *(const f32x4*)&Bs[lr][til * 64 + 32 + lg * 8 + 4];

        // log2(p) = (q*k)*log2e + (bias-12)*log2e  -- directly from MFMA
        f32x4 sv0 = __builtin_amdgcn_mfma_f32_16x16x32_bf16(kf0, qf, cb0, 0, 0, 0);
        f32x4 sv1 = __builtin_amdgcn_mfma_f32_16x16x32_bf16(kf1, qf, cb1, 0, 0, 0);
        f32x4 sv2 = __builtin_amdgcn_mfma_f32_16x16x32_bf16(kf2, qf, cb2, 0, 0, 0);
        f32x4 sv3 = __builtin_amdgcn_mfma_f32_16x16x32_bf16(kf3, qf, cb3, 0, 0, 0);

        // lane-local exp2: one v_exp_f32 per score
        f32x4 e0, e1, e2, e3;
#pragma unroll
        for (int r = 0; r < 4; ++r) {
            e0[r] = fexp2(sv0[r]);
            e1[r] = fexp2(sv1[r]);
            e2[r] = fexp2(sv2[r]);
            e3[r] = fexp2(sv3[r]);
        }

        // pack PV A-fragments fully in-register (s-chunk = lg*8 + j)
        bf16x8 pf0, pf1;
#pragma unroll
        for (int r = 0; r < 4; ++r) {
            pf0[r] = (__bf16)e0[r]; pf0[4 + r] = (__bf16)e1[r];
            pf1[r] = (__bf16)e2[r]; pf1[4 + r] = (__bf16)e3[r];
        }

        o0 = __builtin_amdgcn_mfma_f32_16x16x32_bf16(pf0, vf0, o0, 0, 0, 0);
        o1 = __builtin_amdgcn_mfma_f32_16x16x32_bf16(pf0, vf1, o1, 0, 0, 0);
        ol = __builtin_amdgcn_mfma_f32_16x16x32_bf16(pf0, ones, ol, 0, 0, 0);
        o0 = __builtin_amdgcn_mfma_f32_16x16x32_bf16(pf1, vf2, o0, 0, 0, 0);
        o1 = __builtin_amdgcn_mfma_f32_16x16x32_bf16(pf1, vf3, o1, 0, 0, 0);
        ol = __builtin_amdgcn_mfma_f32_16x16x32_bf16(pf1, ones, ol, 0, 0, 0);
    }

    // normalize and store final attention rows as packed bf16x2
    // att element e of a row maps to d = (e&1)*16 + (e>>1).
#pragma unroll
    for (int r = 0; r < 4; ++r) {
        int t = t0 + lg * 4 + r;
        float inv = 1.0f / ol[r];
        bf16x2 w;
        w[0] = (__bf16)(o0[r] * inv);
        w[1] = (__bf16)(o1[r] * inv);
        *(bf16x2*)&att[((size_t)bh * T_DIM + t) * D_DIM + lr * 2] = w;
    }
}

// ---------------- Kernel 3: output projection ----------------
// grid (64, 4), block 256. X-tile is reconstructed from att during staging: bf16x8 load,
// scatter to Xs at d = (e&1)*16 + (e>>1) (no combine work -- att is already normalized).
__global__ __launch_bounds__(256)
void oproj_kernel(const __bf16* __restrict__ att,
                  const float* __restrict__ Wo, const float* __restrict__ bo,
                  float* __restrict__ out) {
    __shared__ __align__(16) __bf16 Xs[64][136];
    __shared__ __align__(16) __bf16 Ws[64][136];
    const int m0 = blockIdx.x * 64;
    const int n0 = blockIdx.y * 64;
    const int tid = threadIdx.x;
    const int wid = tid >> 6, lane = tid & 63;
    const int wm = (wid & 1) * 32, wn = (wid >> 1) * 32;
    const int lr = lane & 15, lg = lane >> 4;
    const int tb = m0 >> 1;                    // first t of this block (32 t-values)

    f32x4 acc[2][2] = {};
    for (int kc = 0; kc < 2; ++kc) {
        // X-tile staging from att: 1024 chunks of 8 elems (64 m x 4 h x 4 eb)
#pragma unroll
        for (int rep = 0; rep < 4; ++rep) {
            int c = tid + rep * 256;
            int m_loc = c >> 4;                // 0..63
            int rem = c & 15;
            int h_loc = rem >> 2, eb = rem & 3;
            int b = m_loc & 1;                 // m0 is a multiple of 64
            int h = kc * 4 + h_loc;
            int bh = b * H_DIM + h;
            int tl = m_loc >> 1;               // t offset within block
            size_t row = (size_t)bh * T_DIM + tb + tl;
            bf16x8 v = *(const bf16x8*)&att[row * D_DIM + eb * 8];
#pragma unroll
            for (int j = 0; j < 8; ++j) {
                int d = (j & 1) * 16 + eb * 4 + (j >> 1);
                Xs[m_loc][h_loc * 32 + d] = v[j];
            }
        }
        // Wo staging (f32 -> bf16)
        for (int c = tid; c < 2048; c += 256) {
            int row = c >> 5, col = (c & 31) * 4;
            float4 wv = *(const float4*)&Wo[(size_t)(n0 + row) * E_DIM + kc * 128 + col];
            bf16x4 wb;
            wb[0] = (__bf16)wv.x; wb[1] = (__bf16)wv.y; wb[2] = (__bf16)wv.z; wb[3] = (__bf16)wv.w;
            *(bf16x4*)&Ws[row][col] = wb;
        }
        __syncthreads();
#pragma unroll
        for (int ks = 0; ks < 4; ++ks) {
            bf16x8 a0 = *(const bf16x8*)&Xs[wm + lr][ks * 32 + lg * 8];
            bf16x8 a1 = *(const bf16x8*)&Xs[wm + 16 + lr][ks * 32 + lg * 8];
            bf16x8 b0 = *(const bf16x8*)&Ws[wn + lr][ks * 32 + lg * 8];
            bf16x8 b1 = *(const bf16x8*)&Ws[wn + 16 + lr][ks * 32 + lg * 8];
            acc[0][0] = __builtin_amdgcn_mfma_f32_16x16x32_bf16(a0, b0, acc[0][0], 0, 0, 0);
            acc[0][1] = __builtin_amdgcn_mfma_f32_16x16x32_bf16(a0, b1, acc[0][1], 0, 0, 0);
            acc[1][0] = __builtin_amdgcn_mfma_f32_16x16x32_bf16(a1, b0, acc[1][0], 0, 0, 0);
            acc[1][1] = __builtin_amdgcn_mfma_f32_16x16x32_bf16(a1, b1, acc[1][1], 0, 0, 0);
        }
        __syncthreads();
    }
#pragma unroll
    for (int mt = 0; mt < 2; ++mt) {
#pragma unroll
        for (int nt = 0; nt < 2; ++nt) {
            int n = n0 + wn + nt * 16 + lr;
            float bb = bo[n];
#pragma unroll
            for (int r = 0; r < 4; ++r) {
                int m = m0 + wm + mt * 16 + lg * 4 + r;
                out[(size_t)m * E_DIM + n] = acc[mt][nt][r] + bb;
            }
        }
    }
}

extern "C" void kernel_launch(void* const* d_in, const int* in_sizes, int n_in,
                              void* d_out, int out_size, void* d_ws, size_t ws_size,
                              hipStream_t stream) {
    const float* query     = (const float*)d_in[0];
    const float* attn_bias = (const float*)d_in[1];
    const float* Wq = (const float*)d_in[2];
    const float* bq = (const float*)d_in[3];
    const float* Wk = (const float*)d_in[4];
    const float* bk = (const float*)d_in[5];
    const float* Wv = (const float*)d_in[6];
    const float* bv = (const float*)d_in[7];
    const float* Wo = (const float*)d_in[8];
    const float* bo = (const float*)d_in[9];
    float* out = (float*)d_out;

    char* ws = (char*)d_ws;
    __bf16* qhp  = (__bf16*)(ws);                    // [B][H][T][D] 2 MB
    __bf16* kpp  = (__bf16*)(ws + 2097152);          // kperm 2 MB
    __bf16* vpp  = (__bf16*)(ws + 4194304);          // vperm 2 MB
    __bf16* att  = (__bf16*)(ws + 6291456);          // [BH][T][32] bf16 (permuted) 2 MB

    qkv_kernel<<<dim3(M_DIM / 64, 12), 256, 0, stream>>>(
        query, Wq, Wk, Wv, bq, bk, bv, qhp, kpp, vpp);

    attn_kernel<<<dim3((T_DIM / 16) * B_DIM), 512, 0, stream>>>(
        qhp, kpp, vpp, attn_bias, att);

    oproj_kernel<<<dim3(M_DIM / 64, E_DIM / 64), 256, 0, stream>>>(att, Wo, bo, out);
}

// Round 22
// 47.911 us; speedup vs baseline: 1.0705x; 1.0705x over previous
//
#include <hip/hip_runtime.h>
#include <hip/hip_bf16.h>

#define T_DIM 2048
#define B_DIM 2
#define E_DIM 256
#define H_DIM 8
#define D_DIM 32
#define M_DIM (T_DIM*B_DIM)   // 4096
#define SPLIT 4
#define S_CHUNK (T_DIM/SPLIT) // 512
#define BHT (B_DIM*H_DIM*T_DIM) // 32768

typedef __bf16 bf16x8 __attribute__((ext_vector_type(8)));
typedef __bf16 bf16x4 __attribute__((ext_vector_type(4)));
typedef __bf16 bf16x2 __attribute__((ext_vector_type(2)));
typedef float  f32x4  __attribute__((ext_vector_type(4)));

// single-instruction hardware exp2 via compiler builtin (hazards handled by codegen)
static __device__ __forceinline__ float fexp2(float x) {
#if __has_builtin(__builtin_amdgcn_exp2f)
    return __builtin_amdgcn_exp2f(x);
#else
    return exp2f(x);
#endif
}

// ---------------- Kernel 1: fused QKV projection (inline f32->bf16 cvt) ----------------
// grid (64, 12). K and V are written PRE-PERMUTED into MFMA-fragment-linear order:
//   kperm[bh][til][nt][lane]{8}  : lane(lr,lg) holds K[s = til*64+(nt>>1)*32+(nt&1)*4+perm(lr)][lg*8..+7]
//   vperm[bh][til][j ][lane]{8}  : j=kt*2+dt, lane(lr,lg) holds V^T[d=dt*16+lr][s = til*64+kt*32+lg*8..+7]
// q is pre-scaled by (1/sqrt(D))*log2(e) so the QK^T MFMA directly yields log2-domain scores.
// Epilogue routes the permuted scatter through LDS (Ps, 8KB): per-element LDS writes at the
// permuted offsets, then coalesced bf16x8 global stores of the four contiguous 2KB chunks
// each block owns -- eliminates the 2B-scattered-store sector amplification.
__global__ __launch_bounds__(256)
void qkv_kernel(const float* __restrict__ X,
                const float* __restrict__ Wq, const float* __restrict__ Wk, const float* __restrict__ Wv,
                const float* __restrict__ bq, const float* __restrict__ bk, const float* __restrict__ bv,
                __bf16* __restrict__ qh, __bf16* __restrict__ kperm, __bf16* __restrict__ vperm) {
    __shared__ __align__(16) __bf16 Xs[64][136];
    __shared__ __align__(16) __bf16 Ws[64][136];
    __shared__ __align__(16) __bf16 Ps[4][1024];   // staged permuted output (4 x 2KB chunks)
    const int m0 = blockIdx.x * 64;
    const int which = blockIdx.y >> 2;        // 0 q, 1 k, 2 v
    const int n0 = (blockIdx.y & 3) * 64;
    const float* W = (which == 0) ? Wq : (which == 1) ? Wk : Wv;
    const float* bias = (which == 0) ? bq : (which == 1) ? bk : bv;
    const int tid = threadIdx.x;
    const int wid = tid >> 6, lane = tid & 63;
    const int wm = (wid & 1) * 32, wn = (wid >> 1) * 32;
    const int lr = lane & 15, lg = lane >> 4;

    f32x4 acc[2][2] = {};
    for (int kc = 0; kc < 2; ++kc) {
        for (int c = tid; c < 2048; c += 256) {
            int row = c >> 5, col = (c & 31) * 4;
            float4 xv = *(const float4*)&X[(size_t)(m0 + row) * E_DIM + kc * 128 + col];
            float4 wv = *(const float4*)&W[(size_t)(n0 + row) * E_DIM + kc * 128 + col];
            bf16x4 xb, wb;
            xb[0] = (__bf16)xv.x; xb[1] = (__bf16)xv.y; xb[2] = (__bf16)xv.z; xb[3] = (__bf16)xv.w;
            wb[0] = (__bf16)wv.x; wb[1] = (__bf16)wv.y; wb[2] = (__bf16)wv.z; wb[3] = (__bf16)wv.w;
            *(bf16x4*)&Xs[row][col] = xb;
            *(bf16x4*)&Ws[row][col] = wb;
        }
        __syncthreads();
#pragma unroll
        for (int ks = 0; ks < 4; ++ks) {
            bf16x8 a0 = *(const bf16x8*)&Xs[wm + lr][ks * 32 + lg * 8];
            bf16x8 a1 = *(const bf16x8*)&Xs[wm + 16 + lr][ks * 32 + lg * 8];
            bf16x8 b0 = *(const bf16x8*)&Ws[wn + lr][ks * 32 + lg * 8];
            bf16x8 b1 = *(const bf16x8*)&Ws[wn + 16 + lr][ks * 32 + lg * 8];
            acc[0][0] = __builtin_amdgcn_mfma_f32_16x16x32_bf16(a0, b0, acc[0][0], 0, 0, 0);
            acc[0][1] = __builtin_amdgcn_mfma_f32_16x16x32_bf16(a0, b1, acc[0][1], 0, 0, 0);
            acc[1][0] = __builtin_amdgcn_mfma_f32_16x16x32_bf16(a1, b0, acc[1][0], 0, 0, 0);
            acc[1][1] = __builtin_amdgcn_mfma_f32_16x16x32_bf16(a1, b1, acc[1][1], 0, 0, 0);
        }
        __syncthreads();
    }
    const float scale = 0.17677669529663687f * 1.4426950408889634f;  // (1/sqrt(32))*log2(e)
    const int tb = m0 >> 1;                   // first t of this block (multiple of 32)
    const int hl0 = n0 >> 5;                  // first head index covered (even)

    // epilogue phase 1: element-wise permuted scatter INTO LDS
#pragma unroll
    for (int mt = 0; mt < 2; ++mt) {
#pragma unroll
        for (int nt = 0; nt < 2; ++nt) {
            int n = n0 + wn + nt * 16 + lr;            // 0..255
            float bb = bias[n];
            int hl = (n >> 5) - hl0, d = n & 31;       // hl in {0,1}
#pragma unroll
            for (int r = 0; r < 4; ++r) {
                int m = m0 + wm + mt * 16 + lg * 4 + r;
                int tt = (m >> 1) - tb, b = m & 1;     // tt in 0..31
                float v = acc[mt][nt][r] + bb;
                int off;
                if (which == 0) {
                    v *= scale;
                    off = tt * 32 + d;
                } else if (which == 1) {
                    off = ((tt >> 2) & 1) * 512 +
                          ((((d >> 3) << 4) | (((tt >> 3) & 3) << 2) | (tt & 3)) << 3) + (d & 7);
                } else {
                    off = (d >> 4) * 512 +
                          (((((tt >> 3) & 3) << 4) | (d & 15)) << 3) + (tt & 7);
                }
                Ps[b * 2 + hl][off] = (__bf16)v;
            }
        }
    }
    __syncthreads();

    // epilogue phase 2: coalesced copy-out (each chunk is contiguous 2KB in the dst array)
    {
        int combo = tid >> 6, e0 = (tid & 63) * 16;    // 64 threads per 1024-elem chunk
        int bc = combo >> 1, hl = combo & 1;
        int bh = bc * H_DIM + hl0 + hl;
        int til = tb >> 6;
        __bf16* dst;
        if (which == 0) {
            dst = qh + ((size_t)bh * T_DIM + tb) * D_DIM;
        } else if (which == 1) {
            int ntk0 = ((tb >> 5) & 1) << 1;
            dst = kperm + (((size_t)bh * 32 + til) * 4 + ntk0) * 512;
        } else {
            int ktv = (tb >> 5) & 1;
            dst = vperm + (((size_t)bh * 32 + til) * 4 + ktv * 2) * 512;
        }
        *(bf16x8*)(dst + e0)     = *(const bf16x8*)&Ps[combo][e0];
        *(bf16x8*)(dst + e0 + 8) = *(const bf16x8*)&Ps[combo][e0 + 8];
    }
}

// ---------------- Kernel 2: flash attention, QBLK=32, per-wave rotated tile order ----------------
// grid (T/32, B, SPLIT=4) = 512 blocks, block 512 = 8 waves; wave w = head w, 32 q-rows
// (two 16-row subtiles A/B sharing each K/V fragment). combo = lin&7 pins one (b,sp)
// per XCD. Wave wid processes tiles in rotated order (st+wid)&7 (order-independent sums).
// Bias tile [32][512] f32 staged once per block as (bias-12)*log2(e); q pre-scaled by
// log2(e)/sqrt(D) so QK^T MFMA output IS log2(p); exp2 = single v_exp_f32.
// Fixed cap M0=12 exact. Row-sums via MFMA against an all-ones B-fragment.
__global__ __launch_bounds__(512, 4)
void attn_kernel(const __bf16* __restrict__ qh, const __bf16* __restrict__ kperm,
                 const __bf16* __restrict__ vperm, const float* __restrict__ attn_bias,
                 __bf16* __restrict__ po, float* __restrict__ pl) {
    __shared__ __align__(16) float Bs[32][516];
    const int lin = blockIdx.x + (T_DIM / 32) * (blockIdx.y + B_DIM * blockIdx.z);
    const int combo = lin & 7;
    const int b  = combo & 1;
    const int sp = combo >> 1;                 // 0..3
    const int t0 = (lin >> 3) * 32;
    const int tid = threadIdx.x, wid = tid >> 6, lane = tid & 63;
    const int lr = lane & 15, lg = lane >> 4;
    const int bh = b * H_DIM + wid;            // wave = head
    const int sbase = sp * S_CHUNK;
    const int tb0 = sp * 8;                    // 8 tiles of 64 per chunk
    const float LOG2E = 1.4426950408889634f;

    // stage bias tile [32][512] as (b - 12)*log2(e) (all 8 heads share it)
    {
        const float* bsrc = attn_bias + ((size_t)b * T_DIM + t0) * T_DIM + sbase;
        int r = tid >> 4, c0 = (tid & 15) * 4;
#pragma unroll
        for (int rep = 0; rep < 8; ++rep) {
            float4 v = *(const float4*)&bsrc[(size_t)r * T_DIM + rep * 64 + c0];
            float4 w;
            w.x = (v.x - 12.0f) * LOG2E;
            w.y = (v.y - 12.0f) * LOG2E;
            w.z = (v.z - 12.0f) * LOG2E;
            w.w = (v.w - 12.0f) * LOG2E;
            *(float4*)&Bs[r][rep * 64 + c0] = w;
        }
    }
    __syncthreads();

    bf16x8 qfA = *(const bf16x8*)&qh[((size_t)bh * T_DIM + t0 + lr) * D_DIM + lg * 8];
    bf16x8 qfB = *(const bf16x8*)&qh[((size_t)bh * T_DIM + t0 + 16 + lr) * D_DIM + lg * 8];
    const __bf16* kpb = kperm + (size_t)bh * T_DIM * D_DIM + (size_t)lane * 8;
    const __bf16* vpb = vperm + (size_t)bh * T_DIM * D_DIM + (size_t)lane * 8;

    bf16x8 ones;
#pragma unroll
    for (int i = 0; i < 8; ++i) ones[i] = (__bf16)1.0f;

    f32x4 oA0 = {}, oA1 = {}, oB0 = {}, oB1 = {};
    f32x4 olA = {}, olB = {};

#pragma unroll
    for (int st = 0; st < 8; ++st) {
        const int stt = (st + wid) & 7;        // per-wave rotated tile order
        const int til = tb0 + stt;

        // K + V fragment loads (shared by both subtiles): linear 16B/lane, L2-resident
        bf16x8 kf0 = *(const bf16x8*)&kpb[(size_t)(til * 4 + 0) * 512];
        bf16x8 kf1 = *(const bf16x8*)&kpb[(size_t)(til * 4 + 1) * 512];
        bf16x8 kf2 = *(const bf16x8*)&kpb[(size_t)(til * 4 + 2) * 512];
        bf16x8 kf3 = *(const bf16x8*)&kpb[(size_t)(til * 4 + 3) * 512];
        bf16x8 vf0 = *(const bf16x8*)&vpb[(size_t)(til * 4 + 0) * 512];
        bf16x8 vf1 = *(const bf16x8*)&vpb[(size_t)(til * 4 + 1) * 512];
        bf16x8 vf2 = *(const bf16x8*)&vpb[(size_t)(til * 4 + 2) * 512];
        bf16x8 vf3 = *(const bf16x8*)&vpb[(size_t)(til * 4 + 3) * 512];

        // bias C-operands from LDS (subtile A rows lr, subtile B rows 16+lr)
        f32x4 cbA0 = *(const f32x4*)&Bs[lr][stt * 64 +  0 + lg * 8 + 0];
        f32x4 cbA1 = *(const f32x4*)&Bs[lr][stt * 64 +  0 + lg * 8 + 4];
        f32x4 cbA2 = *(const f32x4*)&Bs[lr][stt * 64 + 32 + lg * 8 + 0];
        f32x4 cbA3 = *(const f32x4*)&Bs[lr][stt * 64 + 32 + lg * 8 + 4];
        f32x4 cbB0 = *(const f32x4*)&Bs[16 + lr][stt * 64 +  0 + lg * 8 + 0];
        f32x4 cbB1 = *(const f32x4*)&Bs[16 + lr][stt * 64 +  0 + lg * 8 + 4];
        f32x4 cbB2 = *(const f32x4*)&Bs[16 + lr][stt * 64 + 32 + lg * 8 + 0];
        f32x4 cbB3 = *(const f32x4*)&Bs[16 + lr][stt * 64 + 32 + lg * 8 + 4];

        // log2(p) = (q*k)*log2e + (bias-12)*log2e  -- directly from MFMA
        f32x4 svA0 = __builtin_amdgcn_mfma_f32_16x16x32_bf16(kf0, qfA, cbA0, 0, 0, 0);
        f32x4 svB0 = __builtin_amdgcn_mfma_f32_16x16x32_bf16(kf0, qfB, cbB0, 0, 0, 0);
        f32x4 svA1 = __builtin_amdgcn_mfma_f32_16x16x32_bf16(kf1, qfA, cbA1, 0, 0, 0);
        f32x4 svB1 = __builtin_amdgcn_mfma_f32_16x16x32_bf16(kf1, qfB, cbB1, 0, 0, 0);
        f32x4 svA2 = __builtin_amdgcn_mfma_f32_16x16x32_bf16(kf2, qfA, cbA2, 0, 0, 0);
        f32x4 svB2 = __builtin_amdgcn_mfma_f32_16x16x32_bf16(kf2, qfB, cbB2, 0, 0, 0);
        f32x4 svA3 = __builtin_amdgcn_mfma_f32_16x16x32_bf16(kf3, qfA, cbA3, 0, 0, 0);
        f32x4 svB3 = __builtin_amdgcn_mfma_f32_16x16x32_bf16(kf3, qfB, cbB3, 0, 0, 0);

        // lane-local exp2: one v_exp_f32 per score
        f32x4 eA0, eA1, eA2, eA3, eB0, eB1, eB2, eB3;
#pragma unroll
        for (int r = 0; r < 4; ++r) {
            eA0[r] = fexp2(svA0[r]);
            eA1[r] = fexp2(svA1[r]);
            eA2[r] = fexp2(svA2[r]);
            eA3[r] = fexp2(svA3[r]);
            eB0[r] = fexp2(svB0[r]);
            eB1[r] = fexp2(svB1[r]);
            eB2[r] = fexp2(svB2[r]);
            eB3[r] = fexp2(svB3[r]);
        }

        // pack PV A-fragments fully in-register (s-chunk = lg*8 + j)
        bf16x8 pfA0, pfA1, pfB0, pfB1;
#pragma unroll
        for (int r = 0; r < 4; ++r) {
            pfA0[r] = (__bf16)eA0[r]; pfA0[4 + r] = (__bf16)eA1[r];
            pfA1[r] = (__bf16)eA2[r]; pfA1[4 + r] = (__bf16)eA3[r];
            pfB0[r] = (__bf16)eB0[r]; pfB0[4 + r] = (__bf16)eB1[r];
            pfB1[r] = (__bf16)eB2[r]; pfB1[4 + r] = (__bf16)eB3[r];
        }

        oA0 = __builtin_amdgcn_mfma_f32_16x16x32_bf16(pfA0, vf0, oA0, 0, 0, 0);
        oB0 = __builtin_amdgcn_mfma_f32_16x16x32_bf16(pfB0, vf0, oB0, 0, 0, 0);
        oA1 = __builtin_amdgcn_mfma_f32_16x16x32_bf16(pfA0, vf1, oA1, 0, 0, 0);
        oB1 = __builtin_amdgcn_mfma_f32_16x16x32_bf16(pfB0, vf1, oB1, 0, 0, 0);
        olA = __builtin_amdgcn_mfma_f32_16x16x32_bf16(pfA0, ones, olA, 0, 0, 0);
        olB = __builtin_amdgcn_mfma_f32_16x16x32_bf16(pfB0, ones, olB, 0, 0, 0);
        oA0 = __builtin_amdgcn_mfma_f32_16x16x32_bf16(pfA1, vf2, oA0, 0, 0, 0);
        oB0 = __builtin_amdgcn_mfma_f32_16x16x32_bf16(pfB1, vf2, oB0, 0, 0, 0);
        oA1 = __builtin_amdgcn_mfma_f32_16x16x32_bf16(pfA1, vf3, oA1, 0, 0, 0);
        oB1 = __builtin_amdgcn_mfma_f32_16x16x32_bf16(pfB1, vf3, oB1, 0, 0, 0);
        olA = __builtin_amdgcn_mfma_f32_16x16x32_bf16(pfA1, ones, olA, 0, 0, 0);
        olB = __builtin_amdgcn_mfma_f32_16x16x32_bf16(pfB1, ones, olB, 0, 0, 0);
    }

    // store unnormalized partials as packed bf16x2 (d=lr and d=16+lr in one 4B store).
    // po element e of a row maps to d = (e&1)*16 + (e>>1).
#pragma unroll
    for (int r = 0; r < 4; ++r) {
        int tA = t0 + lg * 4 + r;
        size_t rwA = ((size_t)bh * T_DIM + tA) * SPLIT + sp;
        bf16x2 wA;
        wA[0] = (__bf16)oA0[r];
        wA[1] = (__bf16)oA1[r];
        *(bf16x2*)&po[rwA * D_DIM + lr * 2] = wA;
        size_t rwB = rwA + (size_t)16 * SPLIT;
        bf16x2 wB;
        wB[0] = (__bf16)oB0[r];
        wB[1] = (__bf16)oB1[r];
        *(bf16x2*)&po[rwB * D_DIM + lr * 2] = wB;
    }
    // ol[r] = l for row t0+{0,16}+lg*4+r (all 16 cols identical)
    if (lr == 0) {
        *(f32x4*)&pl[(size_t)sp * BHT + (size_t)bh * T_DIM + t0 + lg * 4] = olA;
        *(f32x4*)&pl[(size_t)sp * BHT + (size_t)bh * T_DIM + t0 + 16 + lg * 4] = olB;
    }
}

// ---------------- Kernel 3: output projection, FUSED with split-combine ----------------
// grid (64, 4), block 256. X-tile is reconstructed directly from po/pl during staging:
// per 8-elem chunk: sum SPLIT=4 bf16x8 partials, scale by invL (cooperatively staged,
// coalesced pl reads), scatter to Xs at d = (e&1)*16 + (e>>1).
__global__ __launch_bounds__(256)
void oproj_kernel(const __bf16* __restrict__ po, const float* __restrict__ pl,
                  const float* __restrict__ Wo, const float* __restrict__ bo,
                  float* __restrict__ out) {
    __shared__ __align__(16) __bf16 Xs[64][136];
    __shared__ __align__(16) __bf16 Ws[64][136];
    __shared__ float invLs[16][32];
    const int m0 = blockIdx.x * 64;
    const int n0 = blockIdx.y * 64;
    const int tid = threadIdx.x;
    const int wid = tid >> 6, lane = tid & 63;
    const int wm = (wid & 1) * 32, wn = (wid >> 1) * 32;
    const int lr = lane & 15, lg = lane >> 4;
    const int tb = m0 >> 1;                    // first t of this block (32 t-values)

    // stage invL for the block's 512 (bh, t) rows: coalesced pl reads (32 consecutive t)
#pragma unroll
    for (int i = 0; i < 2; ++i) {
        int idx = tid + i * 256;               // 0..511
        int bhl = idx >> 5, toff = idx & 31;
        int row = bhl * T_DIM + tb + toff;
        float L = pl[row] + pl[BHT + row] + pl[2 * BHT + row] + pl[3 * BHT + row];
        invLs[bhl][toff] = 1.0f / L;
    }
    __syncthreads();

    f32x4 acc[2][2] = {};
    for (int kc = 0; kc < 2; ++kc) {
        // X-tile staging from po: 1024 chunks of 8 elems (64 m x 4 h x 4 eb)
#pragma unroll
        for (int rep = 0; rep < 4; ++rep) {
            int c = tid + rep * 256;
            int m_loc = c >> 4;                // 0..63
            int rem = c & 15;
            int h_loc = rem >> 2, eb = rem & 3;
            int b = m_loc & 1;                 // m0 is a multiple of 64
            int h = kc * 4 + h_loc;
            int bh = b * H_DIM + h;
            int tl = m_loc >> 1;               // t offset within block
            size_t row = (size_t)bh * T_DIM + tb + tl;
            const __bf16* src = po + row * (SPLIT * D_DIM) + eb * 8;
            bf16x8 v0 = *(const bf16x8*)(src);
            bf16x8 v1 = *(const bf16x8*)(src + D_DIM);
            bf16x8 v2 = *(const bf16x8*)(src + 2 * D_DIM);
            bf16x8 v3 = *(const bf16x8*)(src + 3 * D_DIM);
            float invL = invLs[bh & 15][tl];
#pragma unroll
            for (int j = 0; j < 8; ++j) {
                float s = ((float)v0[j] + (float)v1[j]) + ((float)v2[j] + (float)v3[j]);
                int d = (j & 1) * 16 + eb * 4 + (j >> 1);
                Xs[m_loc][h_loc * 32 + d] = (__bf16)(s * invL);
            }
        }
        // Wo staging (f32 -> bf16)
        for (int c = tid; c < 2048; c += 256) {
            int row = c >> 5, col = (c & 31) * 4;
            float4 wv = *(const float4*)&Wo[(size_t)(n0 + row) * E_DIM + kc * 128 + col];
            bf16x4 wb;
            wb[0] = (__bf16)wv.x; wb[1] = (__bf16)wv.y; wb[2] = (__bf16)wv.z; wb[3] = (__bf16)wv.w;
            *(bf16x4*)&Ws[row][col] = wb;
        }
        __syncthreads();
#pragma unroll
        for (int ks = 0; ks < 4; ++ks) {
            bf16x8 a0 = *(const bf16x8*)&Xs[wm + lr][ks * 32 + lg * 8];
            bf16x8 a1 = *(const bf16x8*)&Xs[wm + 16 + lr][ks * 32 + lg * 8];
            bf16x8 b0 = *(const bf16x8*)&Ws[wn + lr][ks * 32 + lg * 8];
            bf16x8 b1 = *(const bf16x8*)&Ws[wn + 16 + lr][ks * 32 + lg * 8];
            acc[0][0] = __builtin_amdgcn_mfma_f32_16x16x32_bf16(a0, b0, acc[0][0], 0, 0, 0);
            acc[0][1] = __builtin_amdgcn_mfma_f32_16x16x32_bf16(a0, b1, acc[0][1], 0, 0, 0);
            acc[1][0] = __builtin_amdgcn_mfma_f32_16x16x32_bf16(a1, b0, acc[1][0], 0, 0, 0);
            acc[1][1] = __builtin_amdgcn_mfma_f32_16x16x32_bf16(a1, b1, acc[1][1], 0, 0, 0);
        }
        __syncthreads();
    }
#pragma unroll
    for (int mt = 0; mt < 2; ++mt) {
#pragma unroll
        for (int nt = 0; nt < 2; ++nt) {
            int n = n0 + wn + nt * 16 + lr;
            float bb = bo[n];
#pragma unroll
            for (int r = 0; r < 4; ++r) {
                int m = m0 + wm + mt * 16 + lg * 4 + r;
                out[(size_t)m * E_DIM + n] = acc[mt][nt][r] + bb;
            }
        }
    }
}

extern "C" void kernel_launch(void* const* d_in, const int* in_sizes, int n_in,
                              void* d_out, int out_size, void* d_ws, size_t ws_size,
                              hipStream_t stream) {
    const float* query     = (const float*)d_in[0];
    const float* attn_bias = (const float*)d_in[1];
    const float* Wq = (const float*)d_in[2];
    const float* bq = (const float*)d_in[3];
    const float* Wk = (const float*)d_in[4];
    const float* bk = (const float*)d_in[5];
    const float* Wv = (const float*)d_in[6];
    const float* bv = (const float*)d_in[7];
    const float* Wo = (const float*)d_in[8];
    const float* bo = (const float*)d_in[9];
    float* out = (float*)d_out;

    char* ws = (char*)d_ws;
    __bf16* qhp  = (__bf16*)(ws);                    // [B][H][T][D] 2 MB
    __bf16* kpp  = (__bf16*)(ws + 2097152);          // kperm 2 MB
    __bf16* vpp  = (__bf16*)(ws + 4194304);          // vperm 2 MB
    __bf16* po   = (__bf16*)(ws + 6291456);          // [BH*T][SPLIT=4][32] bf16 = 8.4 MB
    float*  pl   = (float*)(ws + 14680064);          // [SPLIT][BH*T] f32 = 0.5 MB

    qkv_kernel<<<dim3(M_DIM / 64, 12), 256, 0, stream>>>(
        query, Wq, Wk, Wv, bq, bk, bv, qhp, kpp, vpp);

    attn_kernel<<<dim3(T_DIM / 32, B_DIM, SPLIT), 512, 0, stream>>>(
        qhp, kpp, vpp, attn_bias, po, pl);

    oproj_kernel<<<dim3(M_DIM / 64, E_DIM / 64), 256, 0, stream>>>(po, pl, Wo, bo, out);
}